// Round 2
// baseline (661.275 us; speedup 1.0000x reference)
//
#include <hip/hip_runtime.h>
#include <cstdint>
#include <cstddef>

// Problem: B=4, T=2048, D=768, H=12, DH=64. SCALE = sqrt(64) = 8 (multiplied!).
#define Bsz 4
#define Tsz 2048
#define Dsz 768
#define Hsz 12
#define DHsz 64
#define Msz (Bsz * Tsz)   // 8192
#define SCALE_F 8.0f

typedef __attribute__((ext_vector_type(8))) short short8;
typedef __attribute__((ext_vector_type(4))) float floatx4;

__device__ __forceinline__ unsigned short f2bf(float f) {
  union { float f; unsigned u; } v; v.f = f;
  unsigned u = v.u;
  unsigned r = u + 0x7fffu + ((u >> 16) & 1u);  // RNE; inputs finite
  return (unsigned short)(r >> 16);
}
__device__ __forceinline__ float bf2f(unsigned short h) {
  union { unsigned u; float f; } v; v.u = ((unsigned)h) << 16; return v.f;
}

// split 16 consecutive f32 into hi/lo bf16 (double-bf16): v ~= hi + lo, err ~2^-18
__device__ __forceinline__ void split16(const float* __restrict__ g,
                                        unsigned short* __restrict__ hi,
                                        unsigned short* __restrict__ lo) {
#pragma unroll
  for (int i = 0; i < 4; ++i) {
    float4 v = reinterpret_cast<const float4*>(g)[i];
    ushort4 h, l;
    h.x = f2bf(v.x); l.x = f2bf(v.x - bf2f(h.x));
    h.y = f2bf(v.y); l.y = f2bf(v.y - bf2f(h.y));
    h.z = f2bf(v.z); l.z = f2bf(v.z - bf2f(h.z));
    h.w = f2bf(v.w); l.w = f2bf(v.w - bf2f(h.w));
    reinterpret_cast<ushort4*>(hi)[i] = h;
    reinterpret_cast<ushort4*>(lo)[i] = l;
  }
}

// ---------------- f32 -> bf16 convert (w_out only) ----------------
__global__ void cvt_f32_bf16(const float* __restrict__ src,
                             unsigned short* __restrict__ dst, int n) {
  int i = (blockIdx.x * blockDim.x + threadIdx.x) * 4;
  int stride = gridDim.x * blockDim.x * 4;
  for (; i < n; i += stride) {
    float4 v = *reinterpret_cast<const float4*>(src + i);
    ushort4 o;
    o.x = f2bf(v.x); o.y = f2bf(v.y); o.z = f2bf(v.z); o.w = f2bf(v.w);
    *reinterpret_cast<ushort4*>(dst + i) = o;
  }
}

// ---------------- QKV GEMM (double-bf16) + scatter ----------------
// W row for col (kk,h,d) is e = d*36 + kk*12 + h. Q,K written as hi/lo pairs,
// V as single bf16, all in [b][h][t][dh].
__launch_bounds__(256)
__global__ void gemm_qkv(const float* __restrict__ x,
                         const float* __restrict__ wq,
                         unsigned short* __restrict__ Qhp,
                         unsigned short* __restrict__ Qlp,
                         unsigned short* __restrict__ Khp,
                         unsigned short* __restrict__ Klp,
                         unsigned short* __restrict__ Vp) {
  __shared__ unsigned short Ah[64][72], Al[64][72];
  __shared__ unsigned short Bh[64][72], Bl[64][72];
  const int mt = blockIdx.x;        // 0..127
  const int nblk = blockIdx.y;      // 0..35
  const int kk = nblk / 12;         // 0:Q 1:K 2:V
  const int h  = nblk % 12;
  const int tid = threadIdx.x;
  const int w = tid >> 6, lane = tid & 63, l16 = lane & 15, quad = lane >> 4;
  const int srow = tid >> 2;
  const int scol = (tid & 3) * 16;

  floatx4 acc[4];
#pragma unroll
  for (int i = 0; i < 4; ++i) acc[i] = (floatx4){0.f, 0.f, 0.f, 0.f};

  const float* gA = x  + (size_t)(mt * 64 + srow) * Dsz + scol;
  const float* gB = wq + (size_t)(srow * 36 + kk * 12 + h) * Dsz + scol;

  for (int kc = 0; kc < Dsz; kc += 64) {
    __syncthreads();
    split16(gA + kc, &Ah[srow][scol], &Al[srow][scol]);
    split16(gB + kc, &Bh[srow][scol], &Bl[srow][scol]);
    __syncthreads();
#pragma unroll
    for (int s = 0; s < 2; ++s) {
      short8 ah = *reinterpret_cast<const short8*>(&Ah[w * 16 + l16][s * 32 + quad * 8]);
      short8 al = *reinterpret_cast<const short8*>(&Al[w * 16 + l16][s * 32 + quad * 8]);
#pragma unroll
      for (int nt = 0; nt < 4; ++nt) {
        short8 bh = *reinterpret_cast<const short8*>(&Bh[nt * 16 + l16][s * 32 + quad * 8]);
        short8 bl = *reinterpret_cast<const short8*>(&Bl[nt * 16 + l16][s * 32 + quad * 8]);
        acc[nt] = __builtin_amdgcn_mfma_f32_16x16x32_bf16(ah, bh, acc[nt], 0, 0, 0);
        acc[nt] = __builtin_amdgcn_mfma_f32_16x16x32_bf16(ah, bl, acc[nt], 0, 0, 0);
        acc[nt] = __builtin_amdgcn_mfma_f32_16x16x32_bf16(al, bh, acc[nt], 0, 0, 0);
      }
    }
  }
  // epilogue: row m -> (b,t); col d = nt*16 + l16
  const int mbase = mt * 64 + w * 16 + quad * 4;
  const int b = mbase >> 11;
  const size_t hoff = (size_t)(b * Hsz + h) * Tsz * DHsz;
  if (kk == 2) {
    unsigned short* dst = Vp + hoff;
#pragma unroll
    for (int nt = 0; nt < 4; ++nt) {
      int d = nt * 16 + l16;
#pragma unroll
      for (int r = 0; r < 4; ++r) {
        int t = (mbase + r) & (Tsz - 1);
        dst[(size_t)t * DHsz + d] = f2bf(acc[nt][r]);
      }
    }
  } else {
    unsigned short* dh_ = ((kk == 0) ? Qhp : Khp) + hoff;
    unsigned short* dl_ = ((kk == 0) ? Qlp : Klp) + hoff;
#pragma unroll
    for (int nt = 0; nt < 4; ++nt) {
      int d = nt * 16 + l16;
#pragma unroll
      for (int r = 0; r < 4; ++r) {
        int t = (mbase + r) & (Tsz - 1);
        float v = acc[nt][r];
        unsigned short hv = f2bf(v);
        dh_[(size_t)t * DHsz + d] = hv;
        dl_[(size_t)t * DHsz + d] = f2bf(v - bf2f(hv));
      }
    }
  }
}

// ---------------- fused flash attention (double-bf16 QK^T) ----------------
// grid (T/64, B*H); block 256 = 4 waves; wave w owns Q rows [w*16, w*16+16)
__launch_bounds__(256)
__global__ void attn(const unsigned short* __restrict__ Qhp,
                     const unsigned short* __restrict__ Qlp,
                     const unsigned short* __restrict__ Khp,
                     const unsigned short* __restrict__ Klp,
                     const unsigned short* __restrict__ Vp,
                     unsigned short* __restrict__ Ob) {
  __shared__ unsigned short vt[64][72];      // V tile transposed: [dh][key]
  __shared__ unsigned short pl[4][16][72];   // per-wave P: [qrow][key]
  const int qt = blockIdx.x;   // 0..31
  const int bh = blockIdx.y;   // 0..47 = b*12+h
  const int tid = threadIdx.x;
  const int w = tid >> 6, lane = tid & 63, l16 = lane & 15, quad = lane >> 4;
  const size_t hoff = (size_t)bh * Tsz * DHsz;
  const unsigned short* Kh = Khp + hoff;
  const unsigned short* Kl = Klp + hoff;
  const unsigned short* Vh = Vp + hoff;

  // Q A-fragments hi/lo: A[m=l16][k=quad*8+j (+32)]
  short8 a_qh[2], a_ql[2];
  {
    const size_t qoff = hoff + (size_t)(qt * 64 + w * 16 + l16) * DHsz + quad * 8;
    a_qh[0] = *reinterpret_cast<const short8*>(Qhp + qoff);
    a_qh[1] = *reinterpret_cast<const short8*>(Qhp + qoff + 32);
    a_ql[0] = *reinterpret_cast<const short8*>(Qlp + qoff);
    a_ql[1] = *reinterpret_cast<const short8*>(Qlp + qoff + 32);
  }

  floatx4 Of[4];
#pragma unroll
  for (int i = 0; i < 4; ++i) Of[i] = (floatx4){0.f, 0.f, 0.f, 0.f};
  float m_i[4] = {-1e30f, -1e30f, -1e30f, -1e30f};
  float l_i[4] = {0.f, 0.f, 0.f, 0.f};

  const int vrow = tid >> 2;
  const int vcol = (tid & 3) * 16;

  for (int kt = 0; kt < Tsz; kt += 64) {
    __syncthreads();
    {   // stage V tile transposed into LDS
      const unsigned short* src = Vh + (size_t)(kt + vrow) * DHsz + vcol;
      short8 v0 = *reinterpret_cast<const short8*>(src);
      short8 v1 = *reinterpret_cast<const short8*>(src + 8);
#pragma unroll
      for (int j = 0; j < 8; ++j) {
        vt[vcol + j][vrow]     = (unsigned short)v0[j];
        vt[vcol + 8 + j][vrow] = (unsigned short)v1[j];
      }
    }
    __syncthreads();

    // S = Q K^T, double-bf16: hi*hi + hi*lo + lo*hi
    floatx4 S[4];
#pragma unroll
    for (int nt = 0; nt < 4; ++nt) {
      floatx4 acc = (floatx4){0.f, 0.f, 0.f, 0.f};
#pragma unroll
      for (int s = 0; s < 2; ++s) {
        size_t koff = (size_t)(kt + nt * 16 + l16) * DHsz + s * 32 + quad * 8;
        short8 bkh = *reinterpret_cast<const short8*>(Kh + koff);
        short8 bkl = *reinterpret_cast<const short8*>(Kl + koff);
        acc = __builtin_amdgcn_mfma_f32_16x16x32_bf16(a_qh[s], bkh, acc, 0, 0, 0);
        acc = __builtin_amdgcn_mfma_f32_16x16x32_bf16(a_qh[s], bkl, acc, 0, 0, 0);
        acc = __builtin_amdgcn_mfma_f32_16x16x32_bf16(a_ql[s], bkh, acc, 0, 0, 0);
      }
      S[nt] = acc;
    }

    // online softmax per C-row (row = quad*4 + r); 16 col-lanes share a row
#pragma unroll
    for (int r = 0; r < 4; ++r) {
      float s0 = S[0][r] * SCALE_F, s1 = S[1][r] * SCALE_F;
      float s2 = S[2][r] * SCALE_F, s3 = S[3][r] * SCALE_F;
      float mx = fmaxf(fmaxf(s0, s1), fmaxf(s2, s3));
      mx = fmaxf(mx, __shfl_xor(mx, 1));
      mx = fmaxf(mx, __shfl_xor(mx, 2));
      mx = fmaxf(mx, __shfl_xor(mx, 4));
      mx = fmaxf(mx, __shfl_xor(mx, 8));
      float mnew = fmaxf(m_i[r], mx);
      float alpha = __expf(m_i[r] - mnew);
      m_i[r] = mnew;
      float p0 = __expf(s0 - mnew), p1 = __expf(s1 - mnew);
      float p2 = __expf(s2 - mnew), p3 = __expf(s3 - mnew);
      float rs = p0 + p1 + p2 + p3;
      rs += __shfl_xor(rs, 1); rs += __shfl_xor(rs, 2);
      rs += __shfl_xor(rs, 4); rs += __shfl_xor(rs, 8);
      l_i[r] = l_i[r] * alpha + rs;
      Of[0][r] *= alpha; Of[1][r] *= alpha; Of[2][r] *= alpha; Of[3][r] *= alpha;
      int prow = quad * 4 + r;  // C-layout -> A-layout via LDS round-trip
      pl[w][prow][ 0 + l16] = f2bf(p0);
      pl[w][prow][16 + l16] = f2bf(p1);
      pl[w][prow][32 + l16] = f2bf(p2);
      pl[w][prow][48 + l16] = f2bf(p3);
    }

    // O += P @ V  (wave-local LDS RAW: wave-synchronous, in-order LDS)
#pragma unroll
    for (int s = 0; s < 2; ++s) {
      short8 ap = *reinterpret_cast<const short8*>(&pl[w][l16][s * 32 + quad * 8]);
#pragma unroll
      for (int nt = 0; nt < 4; ++nt) {
        short8 bv = *reinterpret_cast<const short8*>(&vt[nt * 16 + l16][s * 32 + quad * 8]);
        Of[nt] = __builtin_amdgcn_mfma_f32_16x16x32_bf16(ap, bv, Of[nt], 0, 0, 0);
      }
    }
  }

  // epilogue: O[b, t, h*64 + d] bf16
  const int b = bh / Hsz, h = bh % Hsz;
#pragma unroll
  for (int r = 0; r < 4; ++r) {
    float inv = 1.0f / l_i[r];
    int t = qt * 64 + w * 16 + quad * 4 + r;
    unsigned short* orow = Ob + (size_t)(b * Tsz + t) * Dsz + h * DHsz;
    orow[ 0 + l16] = f2bf(Of[0][r] * inv);
    orow[16 + l16] = f2bf(Of[1][r] * inv);
    orow[32 + l16] = f2bf(Of[2][r] * inv);
    orow[48 + l16] = f2bf(Of[3][r] * inv);
  }
}

// ---------------- output GEMM (single bf16 — error enters linearly) ----------------
__launch_bounds__(256)
__global__ void gemm_out(const unsigned short* __restrict__ ob,
                         const unsigned short* __restrict__ wb,
                         float* __restrict__ out) {
  __shared__ unsigned short As[64][72];
  __shared__ unsigned short Bs[64][72];
  const int mt = blockIdx.x;
  const int n0 = blockIdx.y * 64;
  const int tid = threadIdx.x;
  const int w = tid >> 6, lane = tid & 63, l16 = lane & 15, quad = lane >> 4;
  const int srow = tid >> 2;
  const int scol = (tid & 3) * 16;

  floatx4 acc[4];
#pragma unroll
  for (int i = 0; i < 4; ++i) acc[i] = (floatx4){0.f, 0.f, 0.f, 0.f};

  const unsigned short* gA = ob + (size_t)(mt * 64 + srow) * Dsz + scol;
  const unsigned short* gB = wb + (size_t)(n0 + srow) * Dsz + scol;

  for (int kc = 0; kc < Dsz; kc += 64) {
    __syncthreads();
    *reinterpret_cast<short8*>(&As[srow][scol])     = *reinterpret_cast<const short8*>(gA + kc);
    *reinterpret_cast<short8*>(&As[srow][scol + 8]) = *reinterpret_cast<const short8*>(gA + kc + 8);
    *reinterpret_cast<short8*>(&Bs[srow][scol])     = *reinterpret_cast<const short8*>(gB + kc);
    *reinterpret_cast<short8*>(&Bs[srow][scol + 8]) = *reinterpret_cast<const short8*>(gB + kc + 8);
    __syncthreads();
#pragma unroll
    for (int s = 0; s < 2; ++s) {
      short8 a = *reinterpret_cast<const short8*>(&As[w * 16 + l16][s * 32 + quad * 8]);
#pragma unroll
      for (int nt = 0; nt < 4; ++nt) {
        short8 b = *reinterpret_cast<const short8*>(&Bs[nt * 16 + l16][s * 32 + quad * 8]);
        acc[nt] = __builtin_amdgcn_mfma_f32_16x16x32_bf16(a, b, acc[nt], 0, 0, 0);
      }
    }
  }
  const int mbase = mt * 64 + w * 16 + quad * 4;
#pragma unroll
  for (int nt = 0; nt < 4; ++nt) {
    int n = n0 + nt * 16 + l16;
#pragma unroll
    for (int r = 0; r < 4; ++r) {
      out[(size_t)(mbase + r) * Dsz + n] = acc[nt][r];
    }
  }
}

// ---------------- launch ----------------
extern "C" void kernel_launch(void* const* d_in, const int* in_sizes, int n_in,
                              void* d_out, int out_size, void* d_ws, size_t ws_size,
                              hipStream_t stream) {
  const float* x     = (const float*)d_in[0];   // [4,2048,768]
  const float* w_qkv = (const float*)d_in[1];   // [2304,768]
  const float* w_out = (const float*)d_in[2];   // [768,768]
  float* out = (float*)d_out;                   // [4,2048,768]

  unsigned short* ws = (unsigned short*)d_ws;
  const size_t nWo = (size_t)Dsz * Dsz;               // 589824
  const size_t nHd = (size_t)Bsz * Hsz * Tsz * DHsz;  // 6291456

  unsigned short* wob = ws;
  unsigned short* Qhp = wob + nWo;
  unsigned short* Qlp = Qhp + nHd;
  unsigned short* Khp = Qlp + nHd;
  unsigned short* Klp = Khp + nHd;
  unsigned short* Vp  = Klp + nHd;
  unsigned short* Ob  = Vp + nHd;
  // total ws use: (nWo + 6*nHd) * 2 bytes ~= 73.1 MiB

  cvt_f32_bf16<<<256, 256, 0, stream>>>(w_out, wob, (int)nWo);
  gemm_qkv<<<dim3(128, 36), 256, 0, stream>>>(x, w_qkv, Qhp, Qlp, Khp, Klp, Vp);
  attn<<<dim3(32, 48), 256, 0, stream>>>(Qhp, Qlp, Khp, Klp, Vp, Ob);
  gemm_out<<<dim3(128, 12), 256, 0, stream>>>(Ob, wob, out);
}

// Round 3
// 500.168 us; speedup vs baseline: 1.3221x; 1.3221x over previous
//
#include <hip/hip_runtime.h>
#include <cstdint>
#include <cstddef>

// B=4, T=2048, D=768, H=12, DH=64. SCALE=8 folded into Q at QKV time.
#define Bsz 4
#define Tsz 2048
#define Dsz 768
#define Hsz 12
#define DHsz 64
#define Msz (Bsz * Tsz)   // 8192

typedef __attribute__((ext_vector_type(8))) short short8;
typedef __attribute__((ext_vector_type(4))) float floatx4;

__device__ __forceinline__ unsigned short f2bf(float f) {
  union { float f; unsigned u; } v; v.f = f;
  unsigned u = v.u;
  unsigned r = u + 0x7fffu + ((u >> 16) & 1u);  // RNE; finite inputs
  return (unsigned short)(r >> 16);
}
__device__ __forceinline__ float bf2f(unsigned short h) {
  union { unsigned u; float f; } v; v.u = ((unsigned)h) << 16; return v.f;
}

// split 16 consecutive f32 into hi/lo bf16: v ~= hi + lo (err ~2^-18)
__device__ __forceinline__ void split16(const float* __restrict__ g,
                                        unsigned short* __restrict__ hi,
                                        unsigned short* __restrict__ lo) {
#pragma unroll
  for (int i = 0; i < 4; ++i) {
    float4 v = reinterpret_cast<const float4*>(g)[i];
    ushort4 h, l;
    h.x = f2bf(v.x); l.x = f2bf(v.x - bf2f(h.x));
    h.y = f2bf(v.y); l.y = f2bf(v.y - bf2f(h.y));
    h.z = f2bf(v.z); l.z = f2bf(v.z - bf2f(h.z));
    h.w = f2bf(v.w); l.w = f2bf(v.w - bf2f(h.w));
    reinterpret_cast<ushort4*>(hi)[i] = h;
    reinterpret_cast<ushort4*>(lo)[i] = l;
  }
}

__global__ void cvt_f32_bf16(const float* __restrict__ src,
                             unsigned short* __restrict__ dst, int n) {
  int i = (blockIdx.x * blockDim.x + threadIdx.x) * 4;
  int stride = gridDim.x * blockDim.x * 4;
  for (; i < n; i += stride) {
    float4 v = *reinterpret_cast<const float4*>(src + i);
    ushort4 o;
    o.x = f2bf(v.x); o.y = f2bf(v.y); o.z = f2bf(v.z); o.w = f2bf(v.w);
    *reinterpret_cast<ushort4*>(dst + i) = o;
  }
}

// ---------------- QKV GEMM (double-bf16) + scatter ----------------
// W row for col (kk,h,d): e = d*36 + kk*12 + h.
// Q: *8, split hi/lo -> [b][h][t][dh]. K: split hi/lo -> [b][h][t][dh].
// V: single bf16 TRANSPOSED -> [b][h][dh][t].
__launch_bounds__(256)
__global__ void gemm_qkv(const float* __restrict__ x,
                         const float* __restrict__ wq,
                         unsigned short* __restrict__ Qhp,
                         unsigned short* __restrict__ Qlp,
                         unsigned short* __restrict__ Khp,
                         unsigned short* __restrict__ Klp,
                         unsigned short* __restrict__ Vtp) {
  __shared__ unsigned short Ah[64][72], Al[64][72];
  __shared__ unsigned short Bh[64][72], Bl[64][72];
  const int mt = blockIdx.x;        // 0..127
  const int nblk = blockIdx.y;      // 0..35
  const int kk = nblk / 12;         // 0:Q 1:K 2:V
  const int h  = nblk % 12;
  const int tid = threadIdx.x;
  const int w = tid >> 6, lane = tid & 63, l16 = lane & 15, quad = lane >> 4;
  const int srow = tid >> 2;
  const int scol = (tid & 3) * 16;

  floatx4 acc[4];
#pragma unroll
  for (int i = 0; i < 4; ++i) acc[i] = (floatx4){0.f, 0.f, 0.f, 0.f};

  const float* gA = x  + (size_t)(mt * 64 + srow) * Dsz + scol;
  const float* gB = wq + (size_t)(srow * 36 + kk * 12 + h) * Dsz + scol;

  for (int kc = 0; kc < Dsz; kc += 64) {
    __syncthreads();
    split16(gA + kc, &Ah[srow][scol], &Al[srow][scol]);
    split16(gB + kc, &Bh[srow][scol], &Bl[srow][scol]);
    __syncthreads();
#pragma unroll
    for (int s = 0; s < 2; ++s) {
      short8 ah = *reinterpret_cast<const short8*>(&Ah[w * 16 + l16][s * 32 + quad * 8]);
      short8 al = *reinterpret_cast<const short8*>(&Al[w * 16 + l16][s * 32 + quad * 8]);
#pragma unroll
      for (int nt = 0; nt < 4; ++nt) {
        short8 bh = *reinterpret_cast<const short8*>(&Bh[nt * 16 + l16][s * 32 + quad * 8]);
        acc[nt] = __builtin_amdgcn_mfma_f32_16x16x32_bf16(ah, bh, acc[nt], 0, 0, 0);
        if (kk != 2) {  // V's rounding error enters linearly: hi*hi suffices
          short8 bl = *reinterpret_cast<const short8*>(&Bl[nt * 16 + l16][s * 32 + quad * 8]);
          acc[nt] = __builtin_amdgcn_mfma_f32_16x16x32_bf16(ah, bl, acc[nt], 0, 0, 0);
          acc[nt] = __builtin_amdgcn_mfma_f32_16x16x32_bf16(al, bh, acc[nt], 0, 0, 0);
        }
      }
    }
  }
  const int mbase = mt * 64 + w * 16 + quad * 4;
  const int b = mbase >> 11;
  const size_t hoff = (size_t)(b * Hsz + h) * Tsz * DHsz;
  if (kk == 2) {
    unsigned short* dst = Vtp + hoff;   // [dh][t]
#pragma unroll
    for (int nt = 0; nt < 4; ++nt) {
      int d = nt * 16 + l16;
#pragma unroll
      for (int r = 0; r < 4; ++r) {
        int t = (mbase + r) & (Tsz - 1);
        dst[(size_t)d * Tsz + t] = f2bf(acc[nt][r]);
      }
    }
  } else {
    const float sc = (kk == 0) ? 8.0f : 1.0f;   // fold SCALE into Q
    unsigned short* dh_ = ((kk == 0) ? Qhp : Khp) + hoff;
    unsigned short* dl_ = ((kk == 0) ? Qlp : Klp) + hoff;
#pragma unroll
    for (int nt = 0; nt < 4; ++nt) {
      int d = nt * 16 + l16;
#pragma unroll
      for (int r = 0; r < 4; ++r) {
        int t = (mbase + r) & (Tsz - 1);
        float v = acc[nt][r] * sc;
        unsigned short hv = f2bf(v);
        dh_[(size_t)t * DHsz + d] = hv;
        dl_[(size_t)t * DHsz + d] = f2bf(v - bf2f(hv));
      }
    }
  }
}

// ---------------- fused flash attention, S^T formulation ----------------
// grid (T/128, B*H); block 256 = 4 waves; wave w owns 32 q-rows (2 m-tiles).
// S^T = K @ Q^T via mfma(K_frag, Q_frag): C col=l16=q, row=quad*4+reg=key.
// Softmax state per-lane. PV: O^T = V^T @ P^T, A=V^T from global [dh][t].
// No __syncthreads in the K-loop (P round-trip is wave-local LDS).
__launch_bounds__(256, 3)
__global__ void attn(const unsigned short* __restrict__ Qhp,
                     const unsigned short* __restrict__ Qlp,
                     const unsigned short* __restrict__ Khp,
                     const unsigned short* __restrict__ Klp,
                     const unsigned short* __restrict__ Vtp,
                     unsigned short* __restrict__ Ob) {
  __shared__ unsigned short plT[4][2][16][68];  // [wave][mtile][q][key +4 pad]
  const int qt = blockIdx.x;   // 0..15
  const int bh = blockIdx.y;   // 0..47
  const int tid = threadIdx.x;
  const int w = tid >> 6, lane = tid & 63, l16 = lane & 15, quad = lane >> 4;
  const size_t hoff = (size_t)bh * Tsz * DHsz;
  const unsigned short* Kh = Khp + hoff;
  const unsigned short* Kl = Klp + hoff;
  const unsigned short* Vt = Vtp + hoff;   // [dh][t]

  // Q B-frags (pre-scaled by 8): lane reads its q-row, contiguous dh
  short8 qh[2][2], ql[2][2];
#pragma unroll
  for (int mt = 0; mt < 2; ++mt) {
    const size_t qoff = hoff + (size_t)(qt * 128 + w * 32 + mt * 16 + l16) * DHsz + quad * 8;
    qh[mt][0] = *reinterpret_cast<const short8*>(Qhp + qoff);
    qh[mt][1] = *reinterpret_cast<const short8*>(Qhp + qoff + 32);
    ql[mt][0] = *reinterpret_cast<const short8*>(Qlp + qoff);
    ql[mt][1] = *reinterpret_cast<const short8*>(Qlp + qoff + 32);
  }

  floatx4 Of[2][4];
#pragma unroll
  for (int mt = 0; mt < 2; ++mt)
#pragma unroll
    for (int nt = 0; nt < 4; ++nt) Of[mt][nt] = (floatx4){0.f, 0.f, 0.f, 0.f};
  float m_i[2] = {-1e30f, -1e30f};
  float l_i[2] = {0.f, 0.f};   // per-lane partial (this lane's keys only)

  for (int kt = 0; kt < Tsz; kt += 64) {
    // S^T = K Q^T, double-bf16 (Kh*Qh + Kl*Qh + Kh*Ql)
    floatx4 S[2][4];
#pragma unroll
    for (int mt = 0; mt < 2; ++mt)
#pragma unroll
      for (int nt = 0; nt < 4; ++nt) S[mt][nt] = (floatx4){0.f, 0.f, 0.f, 0.f};
#pragma unroll
    for (int s = 0; s < 2; ++s) {
#pragma unroll
      for (int nt = 0; nt < 4; ++nt) {
        const size_t koff = (size_t)(kt + nt * 16 + l16) * DHsz + s * 32 + quad * 8;
        short8 kf_h = *reinterpret_cast<const short8*>(Kh + koff);
        short8 kf_l = *reinterpret_cast<const short8*>(Kl + koff);
        S[0][nt] = __builtin_amdgcn_mfma_f32_16x16x32_bf16(kf_h, qh[0][s], S[0][nt], 0, 0, 0);
        S[0][nt] = __builtin_amdgcn_mfma_f32_16x16x32_bf16(kf_l, qh[0][s], S[0][nt], 0, 0, 0);
        S[0][nt] = __builtin_amdgcn_mfma_f32_16x16x32_bf16(kf_h, ql[0][s], S[0][nt], 0, 0, 0);
        S[1][nt] = __builtin_amdgcn_mfma_f32_16x16x32_bf16(kf_h, qh[1][s], S[1][nt], 0, 0, 0);
        S[1][nt] = __builtin_amdgcn_mfma_f32_16x16x32_bf16(kf_l, qh[1][s], S[1][nt], 0, 0, 0);
        S[1][nt] = __builtin_amdgcn_mfma_f32_16x16x32_bf16(kf_h, ql[1][s], S[1][nt], 0, 0, 0);
      }
    }

    // per-lane online softmax (keys live in regs+quads; q = l16)
#pragma unroll
    for (int mt = 0; mt < 2; ++mt) {
      float mx = -1e30f;
#pragma unroll
      for (int nt = 0; nt < 4; ++nt)
#pragma unroll
        for (int r = 0; r < 4; ++r) mx = fmaxf(mx, S[mt][nt][r]);
      mx = fmaxf(mx, __shfl_xor(mx, 16));
      mx = fmaxf(mx, __shfl_xor(mx, 32));
      float mnew = fmaxf(m_i[mt], mx);
      float alpha = __expf(m_i[mt] - mnew);
      m_i[mt] = mnew;
      float ls = 0.f;
#pragma unroll
      for (int nt = 0; nt < 4; ++nt) {
        float p0 = __expf(S[mt][nt][0] - mnew);
        float p1 = __expf(S[mt][nt][1] - mnew);
        float p2 = __expf(S[mt][nt][2] - mnew);
        float p3 = __expf(S[mt][nt][3] - mnew);
        ls += (p0 + p1) + (p2 + p3);
        uint2 pk;
        pk.x = (unsigned)f2bf(p0) | ((unsigned)f2bf(p1) << 16);
        pk.y = (unsigned)f2bf(p2) | ((unsigned)f2bf(p3) << 16);
        *reinterpret_cast<uint2*>(&plT[w][mt][l16][nt * 16 + quad * 4]) = pk;
      }
      l_i[mt] = l_i[mt] * alpha + ls;
#pragma unroll
      for (int nt = 0; nt < 4; ++nt) {
        Of[mt][nt][0] *= alpha; Of[mt][nt][1] *= alpha;
        Of[mt][nt][2] *= alpha; Of[mt][nt][3] *= alpha;
      }
    }

    // O^T += V^T @ P^T (wave-local LDS RAW; wave-synchronous)
    short8 pf[2][2];
#pragma unroll
    for (int s = 0; s < 2; ++s) {
      pf[0][s] = *reinterpret_cast<const short8*>(&plT[w][0][l16][s * 32 + quad * 8]);
      pf[1][s] = *reinterpret_cast<const short8*>(&plT[w][1][l16][s * 32 + quad * 8]);
    }
#pragma unroll
    for (int nt = 0; nt < 4; ++nt) {
#pragma unroll
      for (int s = 0; s < 2; ++s) {
        short8 vf = *reinterpret_cast<const short8*>(
            Vt + (size_t)(nt * 16 + l16) * Tsz + kt + s * 32 + quad * 8);
        Of[0][nt] = __builtin_amdgcn_mfma_f32_16x16x32_bf16(vf, pf[0][s], Of[0][nt], 0, 0, 0);
        Of[1][nt] = __builtin_amdgcn_mfma_f32_16x16x32_bf16(vf, pf[1][s], Of[1][nt], 0, 0, 0);
      }
    }
  }

  // epilogue: O[b][t][h*64+dh]; dh = nt*16 + quad*4 + reg, t = ... + l16
  const int b = bh / Hsz, h = bh % Hsz;
#pragma unroll
  for (int mt = 0; mt < 2; ++mt) {
    float ls = l_i[mt];
    ls += __shfl_xor(ls, 16);
    ls += __shfl_xor(ls, 32);
    float inv = 1.0f / ls;
    int t = qt * 128 + w * 32 + mt * 16 + l16;
    unsigned short* orow = Ob + (size_t)(b * Tsz + t) * Dsz + h * DHsz;
#pragma unroll
    for (int nt = 0; nt < 4; ++nt) {
      ushort4 o;
      o.x = f2bf(Of[mt][nt][0] * inv);
      o.y = f2bf(Of[mt][nt][1] * inv);
      o.z = f2bf(Of[mt][nt][2] * inv);
      o.w = f2bf(Of[mt][nt][3] * inv);
      *reinterpret_cast<ushort4*>(&orow[nt * 16 + quad * 4]) = o;
    }
  }
}

// ---------------- output GEMM (single bf16) ----------------
__launch_bounds__(256)
__global__ void gemm_out(const unsigned short* __restrict__ ob,
                         const unsigned short* __restrict__ wb,
                         float* __restrict__ out) {
  __shared__ unsigned short As[64][72];
  __shared__ unsigned short Bs[64][72];
  const int mt = blockIdx.x;
  const int n0 = blockIdx.y * 64;
  const int tid = threadIdx.x;
  const int w = tid >> 6, lane = tid & 63, l16 = lane & 15, quad = lane >> 4;
  const int srow = tid >> 2;
  const int scol = (tid & 3) * 16;

  floatx4 acc[4];
#pragma unroll
  for (int i = 0; i < 4; ++i) acc[i] = (floatx4){0.f, 0.f, 0.f, 0.f};

  const unsigned short* gA = ob + (size_t)(mt * 64 + srow) * Dsz + scol;
  const unsigned short* gB = wb + (size_t)(n0 + srow) * Dsz + scol;

  for (int kc = 0; kc < Dsz; kc += 64) {
    __syncthreads();
    *reinterpret_cast<short8*>(&As[srow][scol])     = *reinterpret_cast<const short8*>(gA + kc);
    *reinterpret_cast<short8*>(&As[srow][scol + 8]) = *reinterpret_cast<const short8*>(gA + kc + 8);
    *reinterpret_cast<short8*>(&Bs[srow][scol])     = *reinterpret_cast<const short8*>(gB + kc);
    *reinterpret_cast<short8*>(&Bs[srow][scol + 8]) = *reinterpret_cast<const short8*>(gB + kc + 8);
    __syncthreads();
#pragma unroll
    for (int s = 0; s < 2; ++s) {
      short8 a = *reinterpret_cast<const short8*>(&As[w * 16 + l16][s * 32 + quad * 8]);
#pragma unroll
      for (int nt = 0; nt < 4; ++nt) {
        short8 b = *reinterpret_cast<const short8*>(&Bs[nt * 16 + l16][s * 32 + quad * 8]);
        acc[nt] = __builtin_amdgcn_mfma_f32_16x16x32_bf16(a, b, acc[nt], 0, 0, 0);
      }
    }
  }
  const int mbase = mt * 64 + w * 16 + quad * 4;
#pragma unroll
  for (int nt = 0; nt < 4; ++nt) {
    int n = n0 + nt * 16 + l16;
#pragma unroll
    for (int r = 0; r < 4; ++r) {
      out[(size_t)(mbase + r) * Dsz + n] = acc[nt][r];
    }
  }
}

// ---------------- launch ----------------
extern "C" void kernel_launch(void* const* d_in, const int* in_sizes, int n_in,
                              void* d_out, int out_size, void* d_ws, size_t ws_size,
                              hipStream_t stream) {
  const float* x     = (const float*)d_in[0];   // [4,2048,768]
  const float* w_qkv = (const float*)d_in[1];   // [2304,768]
  const float* w_out = (const float*)d_in[2];   // [768,768]
  float* out = (float*)d_out;                   // [4,2048,768]

  unsigned short* ws = (unsigned short*)d_ws;
  const size_t nWo = (size_t)Dsz * Dsz;               // 589824
  const size_t nHd = (size_t)Bsz * Hsz * Tsz * DHsz;  // 6291456

  unsigned short* wob = ws;
  unsigned short* Qhp = wob + nWo;
  unsigned short* Qlp = Qhp + nHd;
  unsigned short* Khp = Qlp + nHd;
  unsigned short* Klp = Khp + nHd;
  unsigned short* Vtp = Klp + nHd;
  unsigned short* Ob  = Vtp + nHd;
  // total ws: (nWo + 6*nHd) * 2 B ~= 73.1 MiB

  cvt_f32_bf16<<<256, 256, 0, stream>>>(w_out, wob, (int)nWo);
  gemm_qkv<<<dim3(128, 36), 256, 0, stream>>>(x, w_qkv, Qhp, Qlp, Khp, Klp, Vtp);
  attn<<<dim3(16, 48), 256, 0, stream>>>(Qhp, Qlp, Khp, Klp, Vtp, Ob);
  gemm_out<<<dim3(128, 12), 256, 0, stream>>>(Ob, wob, out);
}

// Round 4
// 322.647 us; speedup vs baseline: 2.0495x; 1.5502x over previous
//
#include <hip/hip_runtime.h>
#include <hip/hip_bf16.h>
#include <cstdint>
#include <cstddef>

// B=4, T=2048, D=768, H=12, DH=64. SCALE=8 folded into Q at QKV time.
#define Bsz 4
#define Tsz 2048
#define Dsz 768
#define Hsz 12
#define DHsz 64
#define Msz (Bsz * Tsz)   // 8192

typedef __attribute__((ext_vector_type(8))) short short8;
typedef __attribute__((ext_vector_type(4))) float floatx4;

__device__ __forceinline__ unsigned short f2bf(float f) {
  union { float f; unsigned u; } v; v.f = f;
  unsigned u = v.u;
  unsigned r = u + 0x7fffu + ((u >> 16) & 1u);  // RNE; finite inputs
  return (unsigned short)(r >> 16);
}
__device__ __forceinline__ float bf2f(unsigned short h) {
  union { unsigned u; float f; } v; v.u = ((unsigned)h) << 16; return v.f;
}
__device__ __forceinline__ unsigned pk_bf2(float a, float b) {
  union { __hip_bfloat162 b2; unsigned u; } cv;
  cv.b2 = __float22bfloat162_rn(make_float2(a, b));  // v_cvt_pk_bf16_f32
  return cv.u;
}

// ---------------- split kernels: f32 -> (hi, lo) bf16 ----------------
__global__ void split_x(const float* __restrict__ src,
                        unsigned short* __restrict__ hi,
                        unsigned short* __restrict__ lo) {
  int i = (blockIdx.x * blockDim.x + threadIdx.x) * 4;   // exact cover
  float4 v = *reinterpret_cast<const float4*>(src + i);
  ushort4 h, l;
  h.x = f2bf(v.x); l.x = f2bf(v.x - bf2f(h.x));
  h.y = f2bf(v.y); l.y = f2bf(v.y - bf2f(h.y));
  h.z = f2bf(v.z); l.z = f2bf(v.z - bf2f(h.z));
  h.w = f2bf(v.w); l.w = f2bf(v.w - bf2f(h.w));
  *reinterpret_cast<ushort4*>(hi + i) = h;
  *reinterpret_cast<ushort4*>(lo + i) = l;
}

// w_qkv [2304][768] -> permuted rows r' = kk*768 + h*64 + d (src row d*36+kk*12+h)
__global__ void split_w(const float* __restrict__ src,
                        unsigned short* __restrict__ hi,
                        unsigned short* __restrict__ lo) {
  int i = (blockIdx.x * blockDim.x + threadIdx.x) * 4;   // exact cover
  int rp = i / Dsz, c = i % Dsz;
  int kk = rp / Dsz;              // rp in [0,2304): kk = rp/768
  int rem = rp - kk * Dsz;
  int h = rem >> 6, d = rem & 63;
  const float* s = src + (size_t)(d * 36 + kk * 12 + h) * Dsz + c;
  float4 v = *reinterpret_cast<const float4*>(s);
  ushort4 hh, ll;
  hh.x = f2bf(v.x); ll.x = f2bf(v.x - bf2f(hh.x));
  hh.y = f2bf(v.y); ll.y = f2bf(v.y - bf2f(hh.y));
  hh.z = f2bf(v.z); ll.z = f2bf(v.z - bf2f(hh.z));
  hh.w = f2bf(v.w); ll.w = f2bf(v.w - bf2f(hh.w));
  *reinterpret_cast<ushort4*>(hi + i) = hh;
  *reinterpret_cast<ushort4*>(lo + i) = ll;
}

__global__ void cvt_f32_bf16(const float* __restrict__ src,
                             unsigned short* __restrict__ dst, int n) {
  int i = (blockIdx.x * blockDim.x + threadIdx.x) * 4;
  int stride = gridDim.x * blockDim.x * 4;
  for (; i < n; i += stride) {
    float4 v = *reinterpret_cast<const float4*>(src + i);
    ushort4 o;
    o.x = f2bf(v.x); o.y = f2bf(v.y); o.z = f2bf(v.z); o.w = f2bf(v.w);
    *reinterpret_cast<ushort4*>(dst + i) = o;
  }
}

// ---------------- QKV GEMM (double-bf16, pre-split inputs) + scatter ----------------
// Q: *8, hi/lo -> [b][h][t][dh]. K: hi/lo -> [b][h][t][dh]. V: bf16 -> [b][h][dh][t].
__launch_bounds__(256)
__global__ void gemm_qkv(const unsigned short* __restrict__ xh,
                         const unsigned short* __restrict__ xl,
                         const unsigned short* __restrict__ wh,
                         const unsigned short* __restrict__ wl,
                         unsigned short* __restrict__ Qhp,
                         unsigned short* __restrict__ Qlp,
                         unsigned short* __restrict__ Khp,
                         unsigned short* __restrict__ Klp,
                         unsigned short* __restrict__ Vtp) {
  __shared__ unsigned short Ah[64][72], Al[64][72];
  __shared__ unsigned short Bh[64][72], Bl[64][72];
  const int mt = blockIdx.x;        // 0..127
  const int nblk = blockIdx.y;      // 0..35
  const int kk = nblk / 12;         // 0:Q 1:K 2:V
  const int h  = nblk % 12;
  const int tid = threadIdx.x;
  const int w = tid >> 6, lane = tid & 63, l16 = lane & 15, quad = lane >> 4;
  const int srow = tid >> 2;
  const int scol = (tid & 3) * 16;

  floatx4 acc[4];
#pragma unroll
  for (int i = 0; i < 4; ++i) acc[i] = (floatx4){0.f, 0.f, 0.f, 0.f};

  const size_t aoff = (size_t)(mt * 64 + srow) * Dsz + scol;
  const size_t boff = (size_t)(kk * Dsz + h * 64 + srow) * Dsz + scol;  // permuted rows

  for (int kc = 0; kc < Dsz; kc += 64) {
    __syncthreads();
    *reinterpret_cast<short8*>(&Ah[srow][scol])     = *reinterpret_cast<const short8*>(xh + aoff + kc);
    *reinterpret_cast<short8*>(&Ah[srow][scol + 8]) = *reinterpret_cast<const short8*>(xh + aoff + kc + 8);
    *reinterpret_cast<short8*>(&Bh[srow][scol])     = *reinterpret_cast<const short8*>(wh + boff + kc);
    *reinterpret_cast<short8*>(&Bh[srow][scol + 8]) = *reinterpret_cast<const short8*>(wh + boff + kc + 8);
    if (kk != 2) {
      *reinterpret_cast<short8*>(&Al[srow][scol])     = *reinterpret_cast<const short8*>(xl + aoff + kc);
      *reinterpret_cast<short8*>(&Al[srow][scol + 8]) = *reinterpret_cast<const short8*>(xl + aoff + kc + 8);
      *reinterpret_cast<short8*>(&Bl[srow][scol])     = *reinterpret_cast<const short8*>(wl + boff + kc);
      *reinterpret_cast<short8*>(&Bl[srow][scol + 8]) = *reinterpret_cast<const short8*>(wl + boff + kc + 8);
    }
    __syncthreads();
#pragma unroll
    for (int s = 0; s < 2; ++s) {
      short8 ah = *reinterpret_cast<const short8*>(&Ah[w * 16 + l16][s * 32 + quad * 8]);
#pragma unroll
      for (int nt = 0; nt < 4; ++nt) {
        short8 bh = *reinterpret_cast<const short8*>(&Bh[nt * 16 + l16][s * 32 + quad * 8]);
        acc[nt] = __builtin_amdgcn_mfma_f32_16x16x32_bf16(ah, bh, acc[nt], 0, 0, 0);
      }
      if (kk != 2) {
        short8 al = *reinterpret_cast<const short8*>(&Al[w * 16 + l16][s * 32 + quad * 8]);
#pragma unroll
        for (int nt = 0; nt < 4; ++nt) {
          short8 bl = *reinterpret_cast<const short8*>(&Bl[nt * 16 + l16][s * 32 + quad * 8]);
          short8 bh = *reinterpret_cast<const short8*>(&Bh[nt * 16 + l16][s * 32 + quad * 8]);
          acc[nt] = __builtin_amdgcn_mfma_f32_16x16x32_bf16(ah, bl, acc[nt], 0, 0, 0);
          acc[nt] = __builtin_amdgcn_mfma_f32_16x16x32_bf16(al, bh, acc[nt], 0, 0, 0);
        }
      }
    }
  }
  const int mbase = mt * 64 + w * 16 + quad * 4;
  const int b = mbase >> 11;
  const size_t hoff = (size_t)(b * Hsz + h) * Tsz * DHsz;
  const int t0 = mbase & (Tsz - 1);
  if (kk == 2) {
    unsigned short* dst = Vtp + hoff;   // [dh][t]
#pragma unroll
    for (int nt = 0; nt < 4; ++nt) {
      int d = nt * 16 + l16;
      uint2 pk;
      pk.x = pk_bf2(acc[nt][0], acc[nt][1]);
      pk.y = pk_bf2(acc[nt][2], acc[nt][3]);
      *reinterpret_cast<uint2*>(&dst[(size_t)d * Tsz + t0]) = pk;
    }
  } else {
    const float sc = (kk == 0) ? 8.0f : 1.0f;   // fold SCALE into Q
    unsigned short* dh_ = ((kk == 0) ? Qhp : Khp) + hoff;
    unsigned short* dl_ = ((kk == 0) ? Qlp : Klp) + hoff;
#pragma unroll
    for (int nt = 0; nt < 4; ++nt) {
      int d = nt * 16 + l16;
#pragma unroll
      for (int r = 0; r < 4; ++r) {
        float v = acc[nt][r] * sc;
        unsigned short hv = f2bf(v);
        dh_[(size_t)(t0 + r) * DHsz + d] = hv;
        dl_[(size_t)(t0 + r) * DHsz + d] = f2bf(v - bf2f(hv));
      }
    }
  }
}

// ---------------- fused flash attention, S^T + LDS-shared K/V ----------------
// 1D grid 768, XCD swizzle: 6 heads per XCD (K/V stays L2-resident).
// block 256 = 4 waves; wave owns 32 q-rows. K/V tiles staged in LDS once per
// block, register-double-buffered. P round-trip via wave-local LDS.
__launch_bounds__(256, 3)
__global__ void attn(const unsigned short* __restrict__ Qhp,
                     const unsigned short* __restrict__ Qlp,
                     const unsigned short* __restrict__ Khp,
                     const unsigned short* __restrict__ Klp,
                     const unsigned short* __restrict__ Vtp,
                     unsigned short* __restrict__ Ob) {
  __shared__ unsigned short Ksh[64][72], Ksl[64][72], Vs[64][72];
  __shared__ unsigned short plT[4][2][16][72];
  const int bid = blockIdx.x;          // 0..767
  const int xcd = bid & 7, slot = bid >> 3;       // 96 slots/XCD
  const int bh = xcd * 6 + (slot >> 4);           // 48 heads, 6 per XCD
  const int qt = slot & 15;                       // 16 q-tiles of 128
  const int tid = threadIdx.x;
  const int w = tid >> 6, lane = tid & 63, l16 = lane & 15, quad = lane >> 4;
  const size_t hoff = (size_t)bh * Tsz * DHsz;
  const unsigned short* Kh = Khp + hoff;
  const unsigned short* Kl = Klp + hoff;
  const unsigned short* Vt = Vtp + hoff;   // [dh][t]

  // staging: thread covers rows {strow, strow+32}, 8 cols from stcol
  const int strow = tid >> 3;          // 0..31
  const int stcol = (tid & 7) * 8;     // 0..56

  // Q B-frags (pre-scaled by 8)
  short8 qh[2][2], ql[2][2];
#pragma unroll
  for (int mt = 0; mt < 2; ++mt) {
    const size_t qoff = hoff + (size_t)(qt * 128 + w * 32 + mt * 16 + l16) * DHsz + quad * 8;
    qh[mt][0] = *reinterpret_cast<const short8*>(Qhp + qoff);
    qh[mt][1] = *reinterpret_cast<const short8*>(Qhp + qoff + 32);
    ql[mt][0] = *reinterpret_cast<const short8*>(Qlp + qoff);
    ql[mt][1] = *reinterpret_cast<const short8*>(Qlp + qoff + 32);
  }

  floatx4 Of[2][4];
#pragma unroll
  for (int mt = 0; mt < 2; ++mt)
#pragma unroll
    for (int nt = 0; nt < 4; ++nt) Of[mt][nt] = (floatx4){0.f, 0.f, 0.f, 0.f};
  float m_i[2] = {-1e30f, -1e30f};
  float l_i[2] = {0.f, 0.f};

  // prefetch tile kt=0 into regs
  short8 rKh[2], rKl[2], rV[2];
#pragma unroll
  for (int p = 0; p < 2; ++p) {
    rKh[p] = *reinterpret_cast<const short8*>(Kh + (size_t)(strow + p * 32) * DHsz + stcol);
    rKl[p] = *reinterpret_cast<const short8*>(Kl + (size_t)(strow + p * 32) * DHsz + stcol);
    rV[p]  = *reinterpret_cast<const short8*>(Vt + (size_t)(strow + p * 32) * Tsz + stcol);
  }

  for (int kt = 0; kt < Tsz; kt += 64) {
    __syncthreads();   // all reads of previous tile done
#pragma unroll
    for (int p = 0; p < 2; ++p) {
      *reinterpret_cast<short8*>(&Ksh[strow + p * 32][stcol]) = rKh[p];
      *reinterpret_cast<short8*>(&Ksl[strow + p * 32][stcol]) = rKl[p];
      *reinterpret_cast<short8*>(&Vs[strow + p * 32][stcol])  = rV[p];
    }
    __syncthreads();   // staging visible
    const int ktn = kt + 64;
    if (ktn < Tsz) {   // fire next tile's loads; consumed next iteration
#pragma unroll
      for (int p = 0; p < 2; ++p) {
        rKh[p] = *reinterpret_cast<const short8*>(Kh + (size_t)(ktn + strow + p * 32) * DHsz + stcol);
        rKl[p] = *reinterpret_cast<const short8*>(Kl + (size_t)(ktn + strow + p * 32) * DHsz + stcol);
        rV[p]  = *reinterpret_cast<const short8*>(Vt + (size_t)(strow + p * 32) * Tsz + ktn + stcol);
      }
    }

    // S^T = K Q^T, double-bf16 (Kh*Qh + Kl*Qh + Kh*Ql)
    floatx4 S[2][4];
#pragma unroll
    for (int mt = 0; mt < 2; ++mt)
#pragma unroll
      for (int nt = 0; nt < 4; ++nt) S[mt][nt] = (floatx4){0.f, 0.f, 0.f, 0.f};
#pragma unroll
    for (int s = 0; s < 2; ++s) {
#pragma unroll
      for (int nt = 0; nt < 4; ++nt) {
        short8 kf_h = *reinterpret_cast<const short8*>(&Ksh[nt * 16 + l16][s * 32 + quad * 8]);
        short8 kf_l = *reinterpret_cast<const short8*>(&Ksl[nt * 16 + l16][s * 32 + quad * 8]);
        S[0][nt] = __builtin_amdgcn_mfma_f32_16x16x32_bf16(kf_h, qh[0][s], S[0][nt], 0, 0, 0);
        S[0][nt] = __builtin_amdgcn_mfma_f32_16x16x32_bf16(kf_l, qh[0][s], S[0][nt], 0, 0, 0);
        S[0][nt] = __builtin_amdgcn_mfma_f32_16x16x32_bf16(kf_h, ql[0][s], S[0][nt], 0, 0, 0);
        S[1][nt] = __builtin_amdgcn_mfma_f32_16x16x32_bf16(kf_h, qh[1][s], S[1][nt], 0, 0, 0);
        S[1][nt] = __builtin_amdgcn_mfma_f32_16x16x32_bf16(kf_l, qh[1][s], S[1][nt], 0, 0, 0);
        S[1][nt] = __builtin_amdgcn_mfma_f32_16x16x32_bf16(kf_h, ql[1][s], S[1][nt], 0, 0, 0);
      }
    }

    // per-lane online softmax (q = l16; keys in regs+quads)
#pragma unroll
    for (int mt = 0; mt < 2; ++mt) {
      float mx = -1e30f;
#pragma unroll
      for (int nt = 0; nt < 4; ++nt)
#pragma unroll
        for (int r = 0; r < 4; ++r) mx = fmaxf(mx, S[mt][nt][r]);
      mx = fmaxf(mx, __shfl_xor(mx, 16));
      mx = fmaxf(mx, __shfl_xor(mx, 32));
      float mnew = fmaxf(m_i[mt], mx);
      float alpha = __expf(m_i[mt] - mnew);
      m_i[mt] = mnew;
      float ls = 0.f;
#pragma unroll
      for (int nt = 0; nt < 4; ++nt) {
        float p0 = __expf(S[mt][nt][0] - mnew);
        float p1 = __expf(S[mt][nt][1] - mnew);
        float p2 = __expf(S[mt][nt][2] - mnew);
        float p3 = __expf(S[mt][nt][3] - mnew);
        ls += (p0 + p1) + (p2 + p3);
        uint2 pk;
        pk.x = pk_bf2(p0, p1);
        pk.y = pk_bf2(p2, p3);
        *reinterpret_cast<uint2*>(&plT[w][mt][l16][nt * 16 + quad * 4]) = pk;
      }
      l_i[mt] = l_i[mt] * alpha + ls;
#pragma unroll
      for (int nt = 0; nt < 4; ++nt) {
        Of[mt][nt][0] *= alpha; Of[mt][nt][1] *= alpha;
        Of[mt][nt][2] *= alpha; Of[mt][nt][3] *= alpha;
      }
    }

    // O^T += V^T @ P^T (wave-local LDS RAW; wave-synchronous)
    short8 pf[2][2];
#pragma unroll
    for (int s = 0; s < 2; ++s) {
      pf[0][s] = *reinterpret_cast<const short8*>(&plT[w][0][l16][s * 32 + quad * 8]);
      pf[1][s] = *reinterpret_cast<const short8*>(&plT[w][1][l16][s * 32 + quad * 8]);
    }
#pragma unroll
    for (int nt = 0; nt < 4; ++nt) {
#pragma unroll
      for (int s = 0; s < 2; ++s) {
        short8 vf = *reinterpret_cast<const short8*>(&Vs[nt * 16 + l16][s * 32 + quad * 8]);
        Of[0][nt] = __builtin_amdgcn_mfma_f32_16x16x32_bf16(vf, pf[0][s], Of[0][nt], 0, 0, 0);
        Of[1][nt] = __builtin_amdgcn_mfma_f32_16x16x32_bf16(vf, pf[1][s], Of[1][nt], 0, 0, 0);
      }
    }
  }

  // epilogue: O[b][t][h*64+dh]; dh = nt*16 + quad*4 + reg, t = ... + l16
  const int b = bh / Hsz, h = bh % Hsz;
#pragma unroll
  for (int mt = 0; mt < 2; ++mt) {
    float ls = l_i[mt];
    ls += __shfl_xor(ls, 16);
    ls += __shfl_xor(ls, 32);
    float inv = 1.0f / ls;
    int t = qt * 128 + w * 32 + mt * 16 + l16;
    unsigned short* orow = Ob + (size_t)(b * Tsz + t) * Dsz + h * DHsz;
#pragma unroll
    for (int nt = 0; nt < 4; ++nt) {
      uint2 pk;
      pk.x = pk_bf2(Of[mt][nt][0] * inv, Of[mt][nt][1] * inv);
      pk.y = pk_bf2(Of[mt][nt][2] * inv, Of[mt][nt][3] * inv);
      *reinterpret_cast<uint2*>(&orow[nt * 16 + quad * 4]) = pk;
    }
  }
}

// ---------------- output GEMM (single bf16) ----------------
__launch_bounds__(256)
__global__ void gemm_out(const unsigned short* __restrict__ ob,
                         const unsigned short* __restrict__ wb,
                         float* __restrict__ out) {
  __shared__ unsigned short As[64][72];
  __shared__ unsigned short Bs[64][72];
  const int mt = blockIdx.x;
  const int n0 = blockIdx.y * 64;
  const int tid = threadIdx.x;
  const int w = tid >> 6, lane = tid & 63, l16 = lane & 15, quad = lane >> 4;
  const int srow = tid >> 2;
  const int scol = (tid & 3) * 16;

  floatx4 acc[4];
#pragma unroll
  for (int i = 0; i < 4; ++i) acc[i] = (floatx4){0.f, 0.f, 0.f, 0.f};

  const unsigned short* gA = ob + (size_t)(mt * 64 + srow) * Dsz + scol;
  const unsigned short* gB = wb + (size_t)(n0 + srow) * Dsz + scol;

  for (int kc = 0; kc < Dsz; kc += 64) {
    __syncthreads();
    *reinterpret_cast<short8*>(&As[srow][scol])     = *reinterpret_cast<const short8*>(gA + kc);
    *reinterpret_cast<short8*>(&As[srow][scol + 8]) = *reinterpret_cast<const short8*>(gA + kc + 8);
    *reinterpret_cast<short8*>(&Bs[srow][scol])     = *reinterpret_cast<const short8*>(gB + kc);
    *reinterpret_cast<short8*>(&Bs[srow][scol + 8]) = *reinterpret_cast<const short8*>(gB + kc + 8);
    __syncthreads();
#pragma unroll
    for (int s = 0; s < 2; ++s) {
      short8 a = *reinterpret_cast<const short8*>(&As[w * 16 + l16][s * 32 + quad * 8]);
#pragma unroll
      for (int nt = 0; nt < 4; ++nt) {
        short8 b = *reinterpret_cast<const short8*>(&Bs[nt * 16 + l16][s * 32 + quad * 8]);
        acc[nt] = __builtin_amdgcn_mfma_f32_16x16x32_bf16(a, b, acc[nt], 0, 0, 0);
      }
    }
  }
  const int mbase = mt * 64 + w * 16 + quad * 4;
#pragma unroll
  for (int nt = 0; nt < 4; ++nt) {
    int n = n0 + nt * 16 + l16;
#pragma unroll
    for (int r = 0; r < 4; ++r) {
      out[(size_t)(mbase + r) * Dsz + n] = acc[nt][r];
    }
  }
}

// ---------------- launch ----------------
extern "C" void kernel_launch(void* const* d_in, const int* in_sizes, int n_in,
                              void* d_out, int out_size, void* d_ws, size_t ws_size,
                              hipStream_t stream) {
  const float* x     = (const float*)d_in[0];   // [4,2048,768]
  const float* w_qkv = (const float*)d_in[1];   // [2304,768]
  const float* w_out = (const float*)d_in[2];   // [768,768]
  float* out = (float*)d_out;                   // [4,2048,768]

  unsigned short* ws = (unsigned short*)d_ws;
  const size_t nX  = (size_t)Msz * Dsz;               // 6291456
  const size_t nWq = (size_t)3 * Dsz * Dsz;           // 1769472
  const size_t nWo = (size_t)Dsz * Dsz;               // 589824
  const size_t nHd = (size_t)Bsz * Hsz * Tsz * DHsz;  // 6291456

  unsigned short* xh  = ws;
  unsigned short* xl  = xh + nX;
  unsigned short* wh  = xl + nX;
  unsigned short* wl  = wh + nWq;
  unsigned short* wob = wl + nWq;
  unsigned short* Qhp = wob + nWo;
  unsigned short* Qlp = Qhp + nHd;
  unsigned short* Khp = Qlp + nHd;
  unsigned short* Klp = Khp + nHd;
  unsigned short* Vtp = Klp + nHd;
  unsigned short* Ob  = xh;   // xh/xl dead after gemm_qkv
  // peak ws use ~96.3 MB

  split_x<<<nX / 4 / 256, 256, 0, stream>>>(x, xh, xl);
  split_w<<<nWq / 4 / 256, 256, 0, stream>>>(w_qkv, wh, wl);
  cvt_f32_bf16<<<256, 256, 0, stream>>>(w_out, wob, (int)nWo);
  gemm_qkv<<<dim3(128, 36), 256, 0, stream>>>(xh, xl, wh, wl, Qhp, Qlp, Khp, Klp, Vtp);
  attn<<<768, 256, 0, stream>>>(Qhp, Qlp, Khp, Klp, Vtp, Ob);
  gemm_out<<<dim3(128, 12), 256, 0, stream>>>(Ob, wob, out);
}